// Round 2
// baseline (391.436 us; speedup 1.0000x reference)
//
#include <hip/hip_runtime.h>
#include <hip/hip_bf16.h>
#include <cstdint>

typedef __bf16 bf16_t;
typedef __bf16 bf16x8 __attribute__((ext_vector_type(8)));
typedef __bf16 bf16x4 __attribute__((ext_vector_type(4)));
typedef float f32x4 __attribute__((ext_vector_type(4)));

static constexpr int B = 16, N = 1024, D = 768;
static constexpr float SCALE = 0.03608439182435161f; // 768^-0.5

// ---------------- helpers ----------------
__device__ __forceinline__ float wave_red_max(float v) {
#pragma unroll
  for (int o = 32; o > 0; o >>= 1) v = fmaxf(v, __shfl_down(v, o, 64));
  return v;
}
__device__ __forceinline__ float wave_red_sum(float v) {
#pragma unroll
  for (int o = 32; o > 0; o >>= 1) v += __shfl_down(v, o, 64);
  return v;
}
__device__ __forceinline__ float block_max(float v, float* sm) {
  v = wave_red_max(v);
  int lane = threadIdx.x & 63, w = threadIdx.x >> 6;
  if (lane == 0) sm[w] = v;
  __syncthreads();
  return fmaxf(fmaxf(sm[0], sm[1]), fmaxf(sm[2], sm[3]));
}
__device__ __forceinline__ float block_sum(float v, float* sm) {
  v = wave_red_sum(v);
  int lane = threadIdx.x & 63, w = threadIdx.x >> 6;
  if (lane == 0) sm[w] = v;
  __syncthreads();
  return sm[0] + sm[1] + sm[2] + sm[3];
}

// ---------------- cast fp32 -> bf16 (4 elems / thread) ----------------
__global__ __launch_bounds__(256) void cast_f32_bf16_4(const float4* __restrict__ in,
                                                       bf16x4* __restrict__ out, int n4) {
  int i = blockIdx.x * 256 + threadIdx.x;
  if (i < n4) {
    float4 v = in[i];
    bf16x4 o;
    o.x = (bf16_t)v.x; o.y = (bf16_t)v.y; o.z = (bf16_t)v.z; o.w = (bf16_t)v.w;
    out[i] = o;
  }
}

// ---------------- transpose bf16 [B][N][D] -> [B][D][N] ----------------
__global__ __launch_bounds__(256) void transpose_bf16(const bf16_t* __restrict__ in,
                                                      bf16_t* __restrict__ out) {
  __shared__ bf16_t t[32][33];
  int b = blockIdx.z;
  int d0 = blockIdx.x * 32;
  int n0 = blockIdx.y * 32;
  int tx = threadIdx.x & 31;
  int ty = threadIdx.x >> 5; // 0..7
  const bf16_t* src = in + (size_t)b * N * D;
  bf16_t* dst = out + (size_t)b * N * D;
#pragma unroll
  for (int r = 0; r < 4; r++) {
    int n = n0 + ty + r * 8;
    t[ty + r * 8][tx] = src[(size_t)n * D + d0 + tx];
  }
  __syncthreads();
#pragma unroll
  for (int r = 0; r < 4; r++) {
    int d = d0 + ty + r * 8;
    dst[(size_t)d * N + n0 + tx] = t[tx][ty + r * 8];
  }
}

// ---------------- positional softmax: pos[p][n] ----------------
__global__ __launch_bounds__(256) void pos_softmax_k(const float* __restrict__ coords,
                                                     const float* __restrict__ pemb,
                                                     float* __restrict__ pos) {
  __shared__ float sm1[4], sm2[4];
  int p = blockIdx.x;
  int tid = threadIdx.x;
  float e[6];
#pragma unroll
  for (int k = 0; k < 6; k++) e[k] = pemb[p * 6 + k];
  float v[4];
#pragma unroll
  for (int i = 0; i < 4; i++) {
    int n = tid + i * 256;
    const float* c = coords + ((size_t)p * N + n) * 6;
    float s = 0.f;
#pragma unroll
    for (int k = 0; k < 6; k++) s += c[k] * e[k];
    v[i] = s;
  }
  float m = block_max(fmaxf(fmaxf(v[0], v[1]), fmaxf(v[2], v[3])), sm1);
  float ex[4], ls = 0.f;
#pragma unroll
  for (int i = 0; i < 4; i++) { ex[i] = __expf(v[i] - m); ls += ex[i]; }
  float sum = block_sum(ls, sm2);
  float inv = 1.f / sum;
#pragma unroll
  for (int i = 0; i < 4; i++) pos[(size_t)p * N + tid + i * 256] = ex[i] * inv;
}

// ---------------- softmax + gate + entropy; writes attn bf16 in place ----------------
__global__ __launch_bounds__(256) void attn_entropy_k(float* __restrict__ S,
                                                      const float* __restrict__ pos,
                                                      const float* __restrict__ gating,
                                                      const float* __restrict__ temp,
                                                      float* __restrict__ hmap) {
  __shared__ float sm1[4], sm2[4], sm3[4];
  size_t row = blockIdx.x; // 0 .. B*N-1
  int q = (int)(row & (size_t)(N - 1));
  int tid = threadIdx.x;
  float* Srow = S + row * N;
  float g = 1.f / (1.f + __expf(-gating[0]));
  float s[4];
#pragma unroll
  for (int i = 0; i < 4; i++) s[i] = Srow[tid + i * 256];
  float m = block_max(fmaxf(fmaxf(s[0], s[1]), fmaxf(s[2], s[3])), sm1);
  float e[4], ls = 0.f;
#pragma unroll
  for (int i = 0; i < 4; i++) { e[i] = __expf(s[i] - m); ls += e[i]; }
  float sum = block_sum(ls, sm2);
  float inv = 1.f / sum;
  const float* prow = pos + (size_t)q * N;
  float a[4], ent = 0.f;
#pragma unroll
  for (int i = 0; i < 4; i++) {
    float patch = e[i] * inv;
    float ps = prow[tid + i * 256];
    a[i] = (1.f - g) * patch + g * ps;
    ent += -a[i] * __logf(a[i] + 1e-8f);
  }
  float E = block_sum(ent, sm3);
  __syncthreads(); // all reads of Srow complete before bf16 overwrite
  bf16_t* arow = (bf16_t*)Srow; // in-place: bf16 row lives in first 2 KB of the 4 KB fp32 slot
#pragma unroll
  for (int i = 0; i < 4; i++) arow[tid + i * 256] = (bf16_t)a[i];
  // hmap = 2*(1 - sigmoid(z)) = 2*sigmoid(-z) = 2/(1+exp(z)),  z = temp*E
  if (tid == 0) hmap[row] = 2.f / (1.f + __expf(temp[0] * E));
}

// ---------------- NT GEMM: C[M][Nc] = A[M][K] * B[Nc][K]^T * scale ----------------
// 64x64 tile, 4 waves (2x2 of 32x32), mfma_f32_16x16x32_bf16.
template <typename OutT>
__global__ __launch_bounds__(256) void gemm_nt(const bf16_t* __restrict__ A, int lda, long long sA,
                                               const bf16_t* __restrict__ Bm, int ldb, long long sB,
                                               OutT* __restrict__ C, int ldc, long long sC,
                                               int K, float scale) {
  __shared__ __align__(16) bf16_t As[64][40]; // +8 pad (16B) keeps 16B-aligned rows, breaks bank stride
  __shared__ __align__(16) bf16_t Bs[64][40];
  const int tid = threadIdx.x;
  const int lane = tid & 63, wave = tid >> 6;
  const int wr = wave >> 1, wc = wave & 1;
  const int quad = lane >> 4, lr = lane & 15;
  const int tileN = blockIdx.x * 64, tileM = blockIdx.y * 64;
  A += (long long)blockIdx.z * sA;
  Bm += (long long)blockIdx.z * sB;
  C += (long long)blockIdx.z * sC;
  const int srow = tid >> 2, scol = (tid & 3) * 8;
  const bf16_t* ag = A + (long long)(tileM + srow) * lda + scol;
  const bf16_t* bg = Bm + (long long)(tileN + srow) * ldb + scol;
  f32x4 acc[2][2];
#pragma unroll
  for (int i = 0; i < 2; i++)
#pragma unroll
    for (int j = 0; j < 2; j++) acc[i][j] = (f32x4){0.f, 0.f, 0.f, 0.f};

  for (int kt = 0; kt < K; kt += 32) {
    *(uint4*)&As[srow][scol] = *(const uint4*)(ag + kt);
    *(uint4*)&Bs[srow][scol] = *(const uint4*)(bg + kt);
    __syncthreads();
    bf16x8 a0 = *(const bf16x8*)&As[wr * 32 + lr][quad * 8];
    bf16x8 a1 = *(const bf16x8*)&As[wr * 32 + 16 + lr][quad * 8];
    bf16x8 b0 = *(const bf16x8*)&Bs[wc * 32 + lr][quad * 8];
    bf16x8 b1 = *(const bf16x8*)&Bs[wc * 32 + 16 + lr][quad * 8];
    acc[0][0] = __builtin_amdgcn_mfma_f32_16x16x32_bf16(a0, b0, acc[0][0], 0, 0, 0);
    acc[0][1] = __builtin_amdgcn_mfma_f32_16x16x32_bf16(a0, b1, acc[0][1], 0, 0, 0);
    acc[1][0] = __builtin_amdgcn_mfma_f32_16x16x32_bf16(a1, b0, acc[1][0], 0, 0, 0);
    acc[1][1] = __builtin_amdgcn_mfma_f32_16x16x32_bf16(a1, b1, acc[1][1], 0, 0, 0);
    __syncthreads();
  }
#pragma unroll
  for (int i = 0; i < 2; i++)
#pragma unroll
    for (int j = 0; j < 2; j++)
#pragma unroll
      for (int r = 0; r < 4; r++) {
        int row = tileM + wr * 32 + i * 16 + quad * 4 + r;
        int col = tileN + wc * 32 + j * 16 + lr;
        float v = acc[i][j][r] * scale;
        C[(long long)row * ldc + col] = (OutT)v;
      }
}

extern "C" void kernel_launch(void* const* d_in, const int* in_sizes, int n_in,
                              void* d_out, int out_size, void* d_ws, size_t ws_size,
                              hipStream_t stream) {
  const float* x = (const float*)d_in[0];      // [B][N][D]
  const float* y = (const float*)d_in[1];      // [B][N][D]
  const float* coords = (const float*)d_in[2]; // [N][N][6]
  const float* W = (const float*)d_in[3];      // [D][D]
  const float* pemb = (const float*)d_in[4];   // [N][6]
  const float* gating = (const float*)d_in[5];
  const float* temp = (const float*)d_in[6];
  float* out = (float*)d_out;
  float* hmap = out + (size_t)B * N * D;

  char* ws = (char*)d_ws;
  bf16_t* xb = (bf16_t*)(ws + 0);          // 24 MB
  bf16_t* yb = (bf16_t*)(ws + 25165824);   // 24 MB
  bf16_t* yT = (bf16_t*)(ws + 50331648);   // 24 MB
  bf16_t* Wb = (bf16_t*)(ws + 75497472);   // 1.125 MB
  bf16_t* kb = (bf16_t*)(ws + 76677120);   // 24 MB
  float* pos = (float*)(ws + 101842944);   // 4 MB
  float* S   = (float*)(ws + 106037248);   // 64 MB  (attn bf16 written in place)

  const int BND = B * N * D; // 12582912

  cast_f32_bf16_4<<<BND / 4 / 256, 256, 0, stream>>>((const float4*)x, (bf16x4*)xb, BND / 4);
  cast_f32_bf16_4<<<BND / 4 / 256, 256, 0, stream>>>((const float4*)y, (bf16x4*)yb, BND / 4);
  cast_f32_bf16_4<<<(D * D / 4 + 255) / 256, 256, 0, stream>>>((const float4*)W, (bf16x4*)Wb, D * D / 4);
  transpose_bf16<<<dim3(D / 32, N / 32, B), 256, 0, stream>>>(yb, yT);
  pos_softmax_k<<<N, 256, 0, stream>>>(coords, pemb, pos);

  // K1: kb[16384][768] = yb * Wb^T
  gemm_nt<bf16_t><<<dim3(D / 64, (B * N) / 64, 1), 256, 0, stream>>>(
      yb, D, 0LL, Wb, D, 0LL, kb, D, 0LL, D, 1.0f);

  // K3: S[b][n][m] = SCALE * x[b] * k[b]^T
  gemm_nt<float><<<dim3(N / 64, N / 64, B), 256, 0, stream>>>(
      xb, D, (long long)N * D, kb, D, (long long)N * D, S, N, (long long)N * N, D, SCALE);

  // K4: softmax + gate + entropy; attn bf16 in place (row stride 2048 bf16)
  attn_entropy_k<<<B * N, 256, 0, stream>>>(S, pos, gating, temp, hmap);

  // K5: out[b][n][d] = attn[b] * y[b]  (B-operand = yT, NT form)
  gemm_nt<float><<<dim3(D / 64, N / 64, B), 256, 0, stream>>>(
      (const bf16_t*)S, 2 * N, (long long)N * 2 * N, yT, N, (long long)N * D, out, D, (long long)N * D, N, 1.0f);
}

// Round 3
// 352.046 us; speedup vs baseline: 1.1119x; 1.1119x over previous
//
#include <hip/hip_runtime.h>
#include <hip/hip_bf16.h>
#include <cstdint>

typedef __bf16 bf16_t;
typedef __bf16 bf16x8 __attribute__((ext_vector_type(8)));
typedef __bf16 bf16x4 __attribute__((ext_vector_type(4)));
typedef float f32x4 __attribute__((ext_vector_type(4)));

static constexpr int B = 16, N = 1024, D = 768;
static constexpr float SCALE = 0.03608439182435161f; // 768^-0.5

// async global->LDS, 16B per lane, wave-uniform LDS base + lane*16
#define ASYNC_COPY16(gptr, lptr)                                                          \
  __builtin_amdgcn_global_load_lds((const __attribute__((address_space(1))) void*)(gptr), \
                                   (__attribute__((address_space(3))) void*)(lptr), 16, 0, 0)

// ---------------- helpers ----------------
__device__ __forceinline__ float wave_red_max(float v) {
#pragma unroll
  for (int o = 32; o > 0; o >>= 1) v = fmaxf(v, __shfl_down(v, o, 64));
  return v;
}
__device__ __forceinline__ float wave_red_sum(float v) {
#pragma unroll
  for (int o = 32; o > 0; o >>= 1) v += __shfl_down(v, o, 64);
  return v;
}
__device__ __forceinline__ float block_max(float v, float* sm) {
  v = wave_red_max(v);
  int lane = threadIdx.x & 63, w = threadIdx.x >> 6;
  if (lane == 0) sm[w] = v;
  __syncthreads();
  return fmaxf(fmaxf(sm[0], sm[1]), fmaxf(sm[2], sm[3]));
}
__device__ __forceinline__ float block_sum(float v, float* sm) {
  v = wave_red_sum(v);
  int lane = threadIdx.x & 63, w = threadIdx.x >> 6;
  if (lane == 0) sm[w] = v;
  __syncthreads();
  return sm[0] + sm[1] + sm[2] + sm[3];
}

// ---------------- cast fp32 -> bf16 (4 elems / thread) ----------------
__global__ __launch_bounds__(256) void cast_f32_bf16_4(const float4* __restrict__ in,
                                                       bf16x4* __restrict__ out, int n4) {
  int i = blockIdx.x * 256 + threadIdx.x;
  if (i < n4) {
    float4 v = in[i];
    bf16x4 o;
    o.x = (bf16_t)v.x; o.y = (bf16_t)v.y; o.z = (bf16_t)v.z; o.w = (bf16_t)v.w;
    out[i] = o;
  }
}

// ---------------- transpose bf16 [B][N][D] -> [B][D][N] ----------------
__global__ __launch_bounds__(256) void transpose_bf16(const bf16_t* __restrict__ in,
                                                      bf16_t* __restrict__ out) {
  __shared__ bf16_t t[32][33];
  int b = blockIdx.z;
  int d0 = blockIdx.x * 32;
  int n0 = blockIdx.y * 32;
  int tx = threadIdx.x & 31;
  int ty = threadIdx.x >> 5; // 0..7
  const bf16_t* src = in + (size_t)b * N * D;
  bf16_t* dst = out + (size_t)b * N * D;
#pragma unroll
  for (int r = 0; r < 4; r++) {
    int n = n0 + ty + r * 8;
    t[ty + r * 8][tx] = src[(size_t)n * D + d0 + tx];
  }
  __syncthreads();
#pragma unroll
  for (int r = 0; r < 4; r++) {
    int d = d0 + ty + r * 8;
    dst[(size_t)d * N + n0 + tx] = t[tx][ty + r * 8];
  }
}

// ---------------- positional softmax: pos[p][n] ----------------
__global__ __launch_bounds__(256) void pos_softmax_k(const float* __restrict__ coords,
                                                     const float* __restrict__ pemb,
                                                     float* __restrict__ pos) {
  __shared__ float sm1[4], sm2[4];
  int p = blockIdx.x;
  int tid = threadIdx.x;
  float e[6];
#pragma unroll
  for (int k = 0; k < 6; k++) e[k] = pemb[p * 6 + k];
  float v[4];
#pragma unroll
  for (int i = 0; i < 4; i++) {
    int n = tid + i * 256;
    const float* c = coords + ((size_t)p * N + n) * 6;
    float s = 0.f;
#pragma unroll
    for (int k = 0; k < 6; k++) s += c[k] * e[k];
    v[i] = s;
  }
  float m = block_max(fmaxf(fmaxf(v[0], v[1]), fmaxf(v[2], v[3])), sm1);
  float ex[4], ls = 0.f;
#pragma unroll
  for (int i = 0; i < 4; i++) { ex[i] = __expf(v[i] - m); ls += ex[i]; }
  float sum = block_sum(ls, sm2);
  float inv = 1.f / sum;
#pragma unroll
  for (int i = 0; i < 4; i++) pos[(size_t)p * N + tid + i * 256] = ex[i] * inv;
}

// ---------------- softmax + gate + entropy; writes attn bf16 in place ----------------
__global__ __launch_bounds__(256) void attn_entropy_k(float* __restrict__ S,
                                                      const float* __restrict__ pos,
                                                      const float* __restrict__ gating,
                                                      const float* __restrict__ temp,
                                                      float* __restrict__ hmap) {
  __shared__ float sm1[4], sm2[4], sm3[4];
  size_t row = blockIdx.x; // 0 .. B*N-1
  int q = (int)(row & (size_t)(N - 1));
  int tid = threadIdx.x;
  float* Srow = S + row * N;
  float g = 1.f / (1.f + __expf(-gating[0]));
  float s[4];
#pragma unroll
  for (int i = 0; i < 4; i++) s[i] = Srow[tid + i * 256];
  float m = block_max(fmaxf(fmaxf(s[0], s[1]), fmaxf(s[2], s[3])), sm1);
  float e[4], ls = 0.f;
#pragma unroll
  for (int i = 0; i < 4; i++) { e[i] = __expf(s[i] - m); ls += e[i]; }
  float sum = block_sum(ls, sm2);
  float inv = 1.f / sum;
  const float* prow = pos + (size_t)q * N;
  float a[4], ent = 0.f;
#pragma unroll
  for (int i = 0; i < 4; i++) {
    float patch = e[i] * inv;
    float ps = prow[tid + i * 256];
    a[i] = (1.f - g) * patch + g * ps;
    ent += -a[i] * __logf(a[i] + 1e-8f);
  }
  float E = block_sum(ent, sm3);
  __syncthreads(); // all reads of Srow complete before bf16 overwrite
  bf16_t* arow = (bf16_t*)Srow; // in-place: bf16 row lives in first 2 KB of the 4 KB fp32 slot
#pragma unroll
  for (int i = 0; i < 4; i++) arow[tid + i * 256] = (bf16_t)a[i];
  // hmap = 2*(1 - sigmoid(z)) = 2/(1+exp(z)),  z = temp*E
  if (tid == 0) hmap[row] = 2.f / (1.f + __expf(temp[0] * E));
}

// ---------------- NT GEMM, m97 structure ----------------
// C[M][Nc] = A[M][K] * B[Nc][K]^T * scale
// 128x128 tile, BK=32, 4 waves in 2x2, each wave 64x64 via 4x4 of 16x16x32 MFMA.
// Staging: global_load_lds 16B/lane, wave-uniform LDS base (no padding; 64B LDS rows).
template <typename OutT>
__global__ __launch_bounds__(256) void gemm_nt_128(const bf16_t* __restrict__ A, int lda, long long sA,
                                                   const bf16_t* __restrict__ Bm, int ldb, long long sB,
                                                   OutT* __restrict__ C, int ldc, long long sC,
                                                   int K, float scale) {
  __shared__ __align__(16) bf16_t As[128 * 32]; // 8 KB, row-major [128][32]
  __shared__ __align__(16) bf16_t Bs[128 * 32]; // 8 KB
  const int tid = threadIdx.x;
  const int lane = tid & 63, wave = tid >> 6;
  const int wr = wave >> 1, wc = wave & 1; // 2x2 wave grid, each 64x64
  const int quad = lane >> 4, lr = lane & 15;
  const int tileN = blockIdx.x * 128, tileM = blockIdx.y * 128;
  A += (long long)blockIdx.z * sA + (long long)tileM * lda;
  Bm += (long long)blockIdx.z * sB + (long long)tileN * ldb;
  C += (long long)blockIdx.z * sC;

  // staging map: issue i of wave covers LDS rows [wave*32 + i*16, +16)
  // lane l -> row += l/4, col = (l&3)*8 (16B chunk). LDS chunk index == lane order.
  const int srow0 = wave * 32 + (lane >> 2);
  const int scol = (lane & 3) * 8;

  f32x4 acc[4][4];
#pragma unroll
  for (int i = 0; i < 4; i++)
#pragma unroll
    for (int j = 0; j < 4; j++) acc[i][j] = (f32x4){0.f, 0.f, 0.f, 0.f};

  for (int kt = 0; kt < K; kt += 32) {
#pragma unroll
    for (int i = 0; i < 2; i++) {
      ASYNC_COPY16(A + (long long)(srow0 + i * 16) * lda + kt + scol,
                   &As[(wave * 32 + i * 16) * 32]); // wave-uniform base
      ASYNC_COPY16(Bm + (long long)(srow0 + i * 16) * ldb + kt + scol,
                   &Bs[(wave * 32 + i * 16) * 32]);
    }
    __syncthreads();
    bf16x8 af[4], bf[4];
#pragma unroll
    for (int i = 0; i < 4; i++) {
      af[i] = *(const bf16x8*)&As[(wr * 64 + i * 16 + lr) * 32 + quad * 8];
      bf[i] = *(const bf16x8*)&Bs[(wc * 64 + i * 16 + lr) * 32 + quad * 8];
    }
#pragma unroll
    for (int mi = 0; mi < 4; mi++)
#pragma unroll
      for (int nj = 0; nj < 4; nj++)
        acc[mi][nj] = __builtin_amdgcn_mfma_f32_16x16x32_bf16(af[mi], bf[nj], acc[mi][nj], 0, 0, 0);
    __syncthreads();
  }
#pragma unroll
  for (int mi = 0; mi < 4; mi++)
#pragma unroll
    for (int nj = 0; nj < 4; nj++)
#pragma unroll
      for (int r = 0; r < 4; r++) {
        int row = tileM + wr * 64 + mi * 16 + quad * 4 + r;
        int col = tileN + wc * 64 + nj * 16 + lr;
        C[(long long)row * ldc + col] = (OutT)(acc[mi][nj][r] * scale);
      }
}

extern "C" void kernel_launch(void* const* d_in, const int* in_sizes, int n_in,
                              void* d_out, int out_size, void* d_ws, size_t ws_size,
                              hipStream_t stream) {
  const float* x = (const float*)d_in[0];      // [B][N][D]
  const float* y = (const float*)d_in[1];      // [B][N][D]
  const float* coords = (const float*)d_in[2]; // [N][N][6]
  const float* W = (const float*)d_in[3];      // [D][D]
  const float* pemb = (const float*)d_in[4];   // [N][6]
  const float* gating = (const float*)d_in[5];
  const float* temp = (const float*)d_in[6];
  float* out = (float*)d_out;
  float* hmap = out + (size_t)B * N * D;

  char* ws = (char*)d_ws;
  bf16_t* xb = (bf16_t*)(ws + 0);          // 24 MB
  bf16_t* yb = (bf16_t*)(ws + 25165824);   // 24 MB
  bf16_t* yT = (bf16_t*)(ws + 50331648);   // 24 MB
  bf16_t* Wb = (bf16_t*)(ws + 75497472);   // 1.125 MB
  bf16_t* kb = (bf16_t*)(ws + 76677120);   // 24 MB
  float* pos = (float*)(ws + 101842944);   // 4 MB
  float* S   = (float*)(ws + 106037248);   // 64 MB  (attn bf16 written in place)

  const int BND = B * N * D; // 12582912

  cast_f32_bf16_4<<<BND / 4 / 256, 256, 0, stream>>>((const float4*)x, (bf16x4*)xb, BND / 4);
  cast_f32_bf16_4<<<BND / 4 / 256, 256, 0, stream>>>((const float4*)y, (bf16x4*)yb, BND / 4);
  cast_f32_bf16_4<<<(D * D / 4 + 255) / 256, 256, 0, stream>>>((const float4*)W, (bf16x4*)Wb, D * D / 4);
  transpose_bf16<<<dim3(D / 32, N / 32, B), 256, 0, stream>>>(yb, yT);
  pos_softmax_k<<<N, 256, 0, stream>>>(coords, pemb, pos);

  // K1: kb[16384][768] = yb * Wb^T
  gemm_nt_128<bf16_t><<<dim3(D / 128, (B * N) / 128, 1), 256, 0, stream>>>(
      yb, D, 0LL, Wb, D, 0LL, kb, D, 0LL, D, 1.0f);

  // K3: S[b][n][m] = SCALE * x[b] * k[b]^T
  gemm_nt_128<float><<<dim3(N / 128, N / 128, B), 256, 0, stream>>>(
      xb, D, (long long)N * D, kb, D, (long long)N * D, S, N, (long long)N * N, D, SCALE);

  // K4: softmax + gate + entropy; attn bf16 in place (row stride 2048 bf16)
  attn_entropy_k<<<B * N, 256, 0, stream>>>(S, pos, gating, temp, hmap);

  // K5: out[b][n][d] = attn[b] * y[b]  (B-operand = yT, NT form)
  gemm_nt_128<float><<<dim3(D / 128, N / 128, B), 256, 0, stream>>>(
      (const bf16_t*)S, 2 * N, (long long)N * 2 * N, yT, N, (long long)N * D, out, D, (long long)N * D, N, 1.0f);
}